// Round 4
// baseline (630.094 us; speedup 1.0000x reference)
//
#include <hip/hip_runtime.h>

#define N_NODES 100000
#define N_EDGES 1000000
#define D_IN    256
#define D_OUT   64

// bucket decomposition: 256 nodes per bucket
#define BKT_SHIFT   8
#define NODES_PER_B 256
#define N_BKT       391            // ceil(100000 / 256)
#define BKT_CAP     3072           // mean 2558, sigma ~51 -> +10 sigma slack
#define EPB         8192           // edges per binning block
#define BIN_BLOCKS  123            // ceil(1e6 / 8192)
#define GEMM_BLOCKS 782            // 3128 waves, 2 tiles/wave, 6250 tiles exact
#define NUM_TILES   6250           // 100000 / 16 exactly

#define CUR_STRIDE  32

typedef __attribute__((ext_vector_type(8))) short short8;
typedef __attribute__((ext_vector_type(4))) float f32x4;

__device__ __forceinline__ unsigned short f2bf(float f) {
    unsigned int u = __float_as_uint(f);
    u = (u + 0x7fffu + ((u >> 16) & 1u)) >> 16;
    return (unsigned short)u;
}

// MFMA + store for one 16-row tile; B read from LDS per use (keeps VGPRs for
// the A-load pipeline). wT pad = 272 shorts (544 B = 8 banks offset/row ->
// 4-way b128 aliasing instead of 8-way at 264).
__device__ __forceinline__ void mfma_store_tile(
    const short8 afrag[8], const unsigned short wT[64][272],
    unsigned short* __restrict__ hiddenBf, int r0, int n16, int quad)
{
    f32x4 acc[4] = {{0.f,0.f,0.f,0.f},{0.f,0.f,0.f,0.f},
                    {0.f,0.f,0.f,0.f},{0.f,0.f,0.f,0.f}};
#pragma unroll
    for (int ct = 0; ct < 4; ++ct) {
#pragma unroll
        for (int kk = 0; kk < 8; ++kk) {
            short8 b = *(const short8*)&wT[ct * 16 + n16][kk * 32 + quad * 8];
            acc[ct] = __builtin_amdgcn_mfma_f32_16x16x32_bf16(
                afrag[kk], b, acc[ct], 0, 0, 0);
        }
    }
    // C/D layout: col = lane&15, row = quad*4 + reg  [m89-verified]
#pragma unroll
    for (int ct = 0; ct < 4; ++ct)
#pragma unroll
        for (int reg = 0; reg < 4; ++reg)
            hiddenBf[(size_t)(r0 + quad * 4 + reg) * D_OUT + ct * 16 + n16]
                = f2bf(acc[ct][reg]);
}

// ---------------------------------------------------------------------------
// Fused dispatch: blocks [0, BIN_BLOCKS) bin edges into bucket windows;
// remaining blocks run the bf16-MFMA GEMM with a 2-tile software pipeline.
// (unchanged from round 3)
// ---------------------------------------------------------------------------
__global__ __launch_bounds__(256, 2) void gemm_bin_kernel(
    const float* __restrict__ x, const float* __restrict__ w,
    unsigned short* __restrict__ hiddenBf,
    const int* __restrict__ row, const int* __restrict__ col,
    const float* __restrict__ adj, int* __restrict__ gCursor,
    int2* __restrict__ edges)
{
    const int t = threadIdx.x;

    if (blockIdx.x < BIN_BLOCKS) {
        // ----- bin path -----
        __shared__ int cnt[N_BKT];
        __shared__ int cbase[N_BKT];
        __shared__ int cur[N_BKT];

        const int e0 = blockIdx.x * EPB;

        for (int i = t; i < N_BKT; i += 256) cnt[i] = 0;
        __syncthreads();

        // pass 1: batch all 32 row loads (32 in flight -> one latency),
        // keep values in registers for pass 4.
        int rreg[32];
#pragma unroll
        for (int u = 0; u < 32; ++u) {
            int e = e0 + t + u * 256;
            rreg[u] = (e < N_EDGES) ? row[e] : -1;
        }
#pragma unroll
        for (int u = 0; u < 32; ++u)
            if (rreg[u] >= 0) atomicAdd(&cnt[rreg[u] >> BKT_SHIFT], 1);
        __syncthreads();

        for (int i = t; i < N_BKT; i += 256) {
            int c = cnt[i];
            cbase[i] = c ? atomicAdd(&gCursor[i * CUR_STRIDE], c) : 0;
            cur[i] = 0;
        }
        __syncthreads();

        // pass 4: chunks of 8; col/adj batched (16 loads in flight),
        // then 8 independent LDS-atomic + store pairs.
#pragma unroll
        for (int u0 = 0; u0 < 32; u0 += 8) {
            int   cc[8]; float vv[8];
#pragma unroll
            for (int u = 0; u < 8; ++u) {
                int e = e0 + t + (u0 + u) * 256;
                if (rreg[u0 + u] >= 0) { cc[u] = col[e]; vv[u] = adj[e]; }
                else                   { cc[u] = 0;      vv[u] = 0.f;    }
            }
#pragma unroll
            for (int u = 0; u < 8; ++u) {
                int r = rreg[u0 + u];
                if (r >= 0) {
                    int b = r >> BKT_SHIFT;
                    int off = cbase[b] + atomicAdd(&cur[b], 1);
                    if (off < BKT_CAP) {  // capacity guard (never trips)
                        edges[b * BKT_CAP + off] =
                            make_int2(((r & (NODES_PER_B - 1)) << 17) | cc[u],
                                      __float_as_int(vv[u]));
                    }
                }
            }
        }
        return;
    }

    // ----- gemm path -----
    __shared__ unsigned short wT[64][272];

    for (int i = 0; i < 64; ++i) {
        int idx = t + i * 256;
        int k = idx >> 6, n = idx & 63;
        wT[n][k] = f2bf(w[idx]);
    }
    __syncthreads();

    const int lane = t & 63;
    const int wid  = t >> 6;
    const int n16  = lane & 15;
    const int quad = lane >> 4;

    const int waveGid = (blockIdx.x - BIN_BLOCKS) * 4 + wid;
    const int t0 = waveGid * 2;
    if (t0 >= NUM_TILES) return;

    float4 lo[8], hi[8];
    short8 afrag[8];

    // prologue: issue all 16 loads of tile t0
    {
        const float* xrow = x + (size_t)(t0 * 16 + n16) * D_IN + quad * 8;
#pragma unroll
        for (int kk = 0; kk < 8; ++kk) {
            lo[kk] = *(const float4*)(xrow + kk * 32);
            hi[kk] = *(const float4*)(xrow + kk * 32 + 4);
        }
    }
    // convert tile t0 (forces one waitcnt), freeing lo/hi
#pragma unroll
    for (int kk = 0; kk < 8; ++kk) {
        short8 a;
        a[0] = (short)f2bf(lo[kk].x); a[1] = (short)f2bf(lo[kk].y);
        a[2] = (short)f2bf(lo[kk].z); a[3] = (short)f2bf(lo[kk].w);
        a[4] = (short)f2bf(hi[kk].x); a[5] = (short)f2bf(hi[kk].y);
        a[6] = (short)f2bf(hi[kk].z); a[7] = (short)f2bf(hi[kk].w);
        afrag[kk] = a;
    }

    const int t1 = t0 + 1;
    const bool have1 = t1 < NUM_TILES;
    if (have1) {
        // issue tile t1's 16 loads BEFORE tile t0's MFMA/store
        const float* xrow = x + (size_t)(t1 * 16 + n16) * D_IN + quad * 8;
#pragma unroll
        for (int kk = 0; kk < 8; ++kk) {
            lo[kk] = *(const float4*)(xrow + kk * 32);
            hi[kk] = *(const float4*)(xrow + kk * 32 + 4);
        }
    }

    mfma_store_tile(afrag, wT, hiddenBf, t0 * 16, n16, quad);

    if (have1) {
#pragma unroll
        for (int kk = 0; kk < 8; ++kk) {
            short8 a;
            a[0] = (short)f2bf(lo[kk].x); a[1] = (short)f2bf(lo[kk].y);
            a[2] = (short)f2bf(lo[kk].z); a[3] = (short)f2bf(lo[kk].w);
            a[4] = (short)f2bf(hi[kk].x); a[5] = (short)f2bf(hi[kk].y);
            a[6] = (short)f2bf(hi[kk].z); a[7] = (short)f2bf(hi[kk].w);
            afrag[kk] = a;
        }
        mfma_store_tile(afrag, wT, hiddenBf, t1 * 16, n16, quad);
    }
}

// ---------------------------------------------------------------------------
// Round 4: bucket-direct aggregation. Replaces csr_kernel + agg_kernel
// (together ~170 us of the 244 us e2e). One block per bucket; the full
// per-bucket output accumulator acc[256 nodes][64 dims] = 64 KB f32 lives
// in LDS, so edges can be consumed UNSORTED straight from the bin windows:
//   broadcast edge record via readlane -> gather 128-B hiddenBf row
//   (L2/L3-resident, batched 8-wide) -> wave-wide LDS float atomicAdd.
// ds_add addresses nl*256B + lane*4: banks = lane%32, 2 lanes/bank = free;
// same-(node,lane) collisions are rare and HW-serialized.
// Epilogue: PReLU + coalesced 64-KB store. No scan, no re-bucketing pass.
// 64 KB LDS -> 2 blocks/CU (16 waves/CU).
// ---------------------------------------------------------------------------
__global__ __launch_bounds__(512, 2) void bucket_agg_kernel(
    const unsigned short* __restrict__ hiddenBf,
    const int2* __restrict__ edges, const int* __restrict__ gCursor,
    const float* __restrict__ prelu_a, float* __restrict__ out)
{
    __shared__ float acc[NODES_PER_B * D_OUT];   // 64 KB

    const int b    = blockIdx.x;
    const int t    = threadIdx.x;
    const int lane = t & 63;
    const int wid  = t >> 6;

    // zero accumulator (float4 -> 8 stores/thread)
    float4* az = (float4*)acc;
#pragma unroll
    for (int i = 0; i < 8; ++i)
        az[t + i * 512] = make_float4(0.f, 0.f, 0.f, 0.f);
    __syncthreads();

    const int base = b * BKT_CAP;
    int size = gCursor[b * CUR_STRIDE];
    if (size > BKT_CAP) size = BKT_CAP;

    // each wave consumes 64-edge batches, strided by 512 across 8 waves
    for (int i0 = wid * 64; i0 < size; i0 += 512) {
        int take = size - i0;
        if (take > 64) take = 64;
        int2 rec = make_int2(0, 0);
        if (lane < take) rec = edges[base + i0 + lane];

        int j = 0;
        for (; j + 8 <= take; j += 8) {
            int nl[8]; int c[8]; float v[8]; float h[8];
#pragma unroll
            for (int u = 0; u < 8; ++u) {
                int rx = __builtin_amdgcn_readlane(rec.x, j + u);
                nl[u] = rx >> 17;
                c[u]  = rx & 0x1FFFF;
                v[u]  = __int_as_float(__builtin_amdgcn_readlane(rec.y, j + u));
            }
#pragma unroll
            for (int u = 0; u < 8; ++u)
                h[u] = __uint_as_float(
                    (unsigned)hiddenBf[(size_t)c[u] * D_OUT + lane] << 16);
#pragma unroll
            for (int u = 0; u < 8; ++u)
                atomicAdd(&acc[nl[u] * D_OUT + lane], v[u] * h[u]);
        }
        for (; j < take; ++j) {
            int rx = __builtin_amdgcn_readlane(rec.x, j);
            float v = __int_as_float(__builtin_amdgcn_readlane(rec.y, j));
            float h = __uint_as_float(
                (unsigned)hiddenBf[(size_t)(rx & 0x1FFFF) * D_OUT + lane] << 16);
            atomicAdd(&acc[(rx >> 17) * D_OUT + lane], v * h);
        }
    }
    __syncthreads();

    // epilogue: PReLU + coalesced store (2 KB per instruction)
    const float a = prelu_a[0];
    const int node0 = b * NODES_PER_B;
#pragma unroll
    for (int i = 0; i < 32; ++i) {
        int idx  = t + i * 512;                  // 0 .. 16383
        int node = node0 + (idx >> 6);
        if (node < N_NODES) {
            float s = acc[idx];
            out[(size_t)node * D_OUT + (idx & 63)] = s > 0.f ? s : a * s;
        }
    }
}

// ---------------------------------------------------------------------------
extern "C" void kernel_launch(void* const* d_in, const int* in_sizes, int n_in,
                              void* d_out, int out_size, void* d_ws, size_t ws_size,
                              hipStream_t stream)
{
    const float* x       = (const float*)d_in[0];
    const float* w       = (const float*)d_in[1];
    const float* adj     = (const float*)d_in[2];
    const float* prelu_a = (const float*)d_in[3];
    const int*   row     = (const int*)d_in[4];
    const int*   col     = (const int*)d_in[5];
    float* out = (float*)d_out;

    // workspace layout (bytes)
    char* ws = (char*)d_ws;
    unsigned short* hiddenBf = (unsigned short*)(ws);        // 12,800,000
    int2*  edges    = (int2*)        (ws + 12800000);        //  9,609,216
    int*   gCursor  = (int*)         (ws + 22409216);        //     50,048 (391 x 128B)

    hipMemsetAsync(gCursor, 0, N_BKT * CUR_STRIDE * sizeof(int), stream);

    gemm_bin_kernel<<<BIN_BLOCKS + GEMM_BLOCKS, 256, 0, stream>>>(
        x, w, hiddenBf, row, col, adj, gCursor, edges);

    bucket_agg_kernel<<<N_BKT, 512, 0, stream>>>(
        hiddenBf, edges, gCursor, prelu_a, out);
}

// Round 5
// 243.035 us; speedup vs baseline: 2.5926x; 2.5926x over previous
//
#include <hip/hip_runtime.h>

#define N_NODES 100000
#define N_EDGES 1000000
#define D_IN    256
#define D_OUT   64

// Round 5: bucket = 32 nodes (BKT_SHIFT 5). 100000/32 = 3125 buckets EXACT.
// Aggregation is one WAVE per bucket with an exclusive 8-KB LDS accumulator
// -> zero atomics on the agg hot path (round-4's f32 LDS atomicAdd measured
// ~442us: ~256 cyc per wave-wide atomic = per-lane-serialized RMW).
#define BKT_SHIFT   5
#define NODES_PER_BKT 32
#define N_BKT       3125           // 100000 / 32 exact
#define BKT_CAP     512            // mean 320, sigma ~18 -> +10.7 sigma slack
#define EPB         8192           // edges per binning block
#define BIN_BLOCKS  123            // ceil(1e6 / 8192)
#define GEMM_BLOCKS 782            // 3128 waves, 2 tiles/wave, 6250 tiles exact
#define NUM_TILES   6250           // 100000 / 16 exactly
#define AGG_BLOCKS  391            // ceil(3125 buckets / 8 waves)

typedef __attribute__((ext_vector_type(8))) short short8;
typedef __attribute__((ext_vector_type(4))) float f32x4;

__device__ __forceinline__ unsigned short f2bf(float f) {
    unsigned int u = __float_as_uint(f);
    u = (u + 0x7fffu + ((u >> 16) & 1u)) >> 16;
    return (unsigned short)u;
}

// MFMA + store for one 16-row tile; B read from LDS per use (keeps VGPRs for
// the A-load pipeline). wT pad = 272 shorts (544 B = 8 banks offset/row ->
// 4-way b128 aliasing instead of 8-way at 264).
__device__ __forceinline__ void mfma_store_tile(
    const short8 afrag[8], const unsigned short wT[64][272],
    unsigned short* __restrict__ hiddenBf, int r0, int n16, int quad)
{
    f32x4 acc[4] = {{0.f,0.f,0.f,0.f},{0.f,0.f,0.f,0.f},
                    {0.f,0.f,0.f,0.f},{0.f,0.f,0.f,0.f}};
#pragma unroll
    for (int ct = 0; ct < 4; ++ct) {
#pragma unroll
        for (int kk = 0; kk < 8; ++kk) {
            short8 b = *(const short8*)&wT[ct * 16 + n16][kk * 32 + quad * 8];
            acc[ct] = __builtin_amdgcn_mfma_f32_16x16x32_bf16(
                afrag[kk], b, acc[ct], 0, 0, 0);
        }
    }
    // C/D layout: col = lane&15, row = quad*4 + reg  [m89-verified]
#pragma unroll
    for (int ct = 0; ct < 4; ++ct)
#pragma unroll
        for (int reg = 0; reg < 4; ++reg)
            hiddenBf[(size_t)(r0 + quad * 4 + reg) * D_OUT + ct * 16 + n16]
                = f2bf(acc[ct][reg]);
}

// ---------------------------------------------------------------------------
// Fused dispatch: blocks [0, BIN_BLOCKS) bin edges into 32-node bucket
// windows; remaining blocks run the bf16-MFMA GEMM (unchanged from round 3).
// Bin LDS: 3 x 3125 x 4 B = 37.5 KB; per-bucket atomic collisions drop 8x
// vs the 256-node buckets.
// ---------------------------------------------------------------------------
__global__ __launch_bounds__(256, 2) void gemm_bin_kernel(
    const float* __restrict__ x, const float* __restrict__ w,
    unsigned short* __restrict__ hiddenBf,
    const int* __restrict__ row, const int* __restrict__ col,
    const float* __restrict__ adj, int* __restrict__ gCursor,
    int2* __restrict__ edges)
{
    const int t = threadIdx.x;

    if (blockIdx.x < BIN_BLOCKS) {
        // ----- bin path -----
        __shared__ int cnt[N_BKT];
        __shared__ int cbase[N_BKT];
        __shared__ int cur[N_BKT];

        const int e0 = blockIdx.x * EPB;

        for (int i = t; i < N_BKT; i += 256) cnt[i] = 0;
        __syncthreads();

        // pass 1: batch all 32 row loads (32 in flight -> one latency),
        // keep values in registers for pass 4.
        int rreg[32];
#pragma unroll
        for (int u = 0; u < 32; ++u) {
            int e = e0 + t + u * 256;
            rreg[u] = (e < N_EDGES) ? row[e] : -1;
        }
#pragma unroll
        for (int u = 0; u < 32; ++u)
            if (rreg[u] >= 0) atomicAdd(&cnt[rreg[u] >> BKT_SHIFT], 1);
        __syncthreads();

        for (int i = t; i < N_BKT; i += 256) {
            int c = cnt[i];
            cbase[i] = c ? atomicAdd(&gCursor[i], c) : 0;
            cur[i] = 0;
        }
        __syncthreads();

        // pass 4: chunks of 8; col/adj batched (16 loads in flight),
        // then 8 independent LDS-atomic + store pairs.
#pragma unroll
        for (int u0 = 0; u0 < 32; u0 += 8) {
            int   cc[8]; float vv[8];
#pragma unroll
            for (int u = 0; u < 8; ++u) {
                int e = e0 + t + (u0 + u) * 256;
                if (rreg[u0 + u] >= 0) { cc[u] = col[e]; vv[u] = adj[e]; }
                else                   { cc[u] = 0;      vv[u] = 0.f;    }
            }
#pragma unroll
            for (int u = 0; u < 8; ++u) {
                int r = rreg[u0 + u];
                if (r >= 0) {
                    int b = r >> BKT_SHIFT;
                    int off = cbase[b] + atomicAdd(&cur[b], 1);
                    if (off < BKT_CAP) {  // capacity guard (never trips)
                        edges[b * BKT_CAP + off] =
                            make_int2(((r & (NODES_PER_BKT - 1)) << 17) | cc[u],
                                      __float_as_int(vv[u]));
                    }
                }
            }
        }
        return;
    }

    // ----- gemm path -----
    __shared__ unsigned short wT[64][272];

    for (int i = 0; i < 64; ++i) {
        int idx = t + i * 256;
        int k = idx >> 6, n = idx & 63;
        wT[n][k] = f2bf(w[idx]);
    }
    __syncthreads();

    const int lane = t & 63;
    const int wid  = t >> 6;
    const int n16  = lane & 15;
    const int quad = lane >> 4;

    const int waveGid = (blockIdx.x - BIN_BLOCKS) * 4 + wid;
    const int t0 = waveGid * 2;
    if (t0 >= NUM_TILES) return;

    float4 lo[8], hi[8];
    short8 afrag[8];

    // prologue: issue all 16 loads of tile t0
    {
        const float* xrow = x + (size_t)(t0 * 16 + n16) * D_IN + quad * 8;
#pragma unroll
        for (int kk = 0; kk < 8; ++kk) {
            lo[kk] = *(const float4*)(xrow + kk * 32);
            hi[kk] = *(const float4*)(xrow + kk * 32 + 4);
        }
    }
    // convert tile t0 (forces one waitcnt), freeing lo/hi
#pragma unroll
    for (int kk = 0; kk < 8; ++kk) {
        short8 a;
        a[0] = (short)f2bf(lo[kk].x); a[1] = (short)f2bf(lo[kk].y);
        a[2] = (short)f2bf(lo[kk].z); a[3] = (short)f2bf(lo[kk].w);
        a[4] = (short)f2bf(hi[kk].x); a[5] = (short)f2bf(hi[kk].y);
        a[6] = (short)f2bf(hi[kk].z); a[7] = (short)f2bf(hi[kk].w);
        afrag[kk] = a;
    }

    const int t1 = t0 + 1;
    const bool have1 = t1 < NUM_TILES;
    if (have1) {
        // issue tile t1's 16 loads BEFORE tile t0's MFMA/store
        const float* xrow = x + (size_t)(t1 * 16 + n16) * D_IN + quad * 8;
#pragma unroll
        for (int kk = 0; kk < 8; ++kk) {
            lo[kk] = *(const float4*)(xrow + kk * 32);
            hi[kk] = *(const float4*)(xrow + kk * 32 + 4);
        }
    }

    mfma_store_tile(afrag, wT, hiddenBf, t0 * 16, n16, quad);

    if (have1) {
#pragma unroll
        for (int kk = 0; kk < 8; ++kk) {
            short8 a;
            a[0] = (short)f2bf(lo[kk].x); a[1] = (short)f2bf(lo[kk].y);
            a[2] = (short)f2bf(lo[kk].z); a[3] = (short)f2bf(lo[kk].w);
            a[4] = (short)f2bf(hi[kk].x); a[5] = (short)f2bf(hi[kk].y);
            a[6] = (short)f2bf(hi[kk].z); a[7] = (short)f2bf(hi[kk].w);
            afrag[kk] = a;
        }
        mfma_store_tile(afrag, wT, hiddenBf, t1 * 16, n16, quad);
    }
}

// ---------------------------------------------------------------------------
// Round 5: ownership-partitioned bucket aggregation. One wave per 32-node
// bucket; per-wave EXCLUSIVE 8-KB LDS accumulator -> non-atomic
// ds_read+fmac+ds_write RMW (DS pipe is in-order per wave, and the compiler
// preserves RMW order since it cannot disprove aliasing of runtime indices).
// Edges consumed unsorted straight from bin windows: readlane broadcast,
// gathers batched 8-deep for MLP. No barriers anywhere (waves independent).
// 8 waves x 8 KB = 64 KB LDS -> 2 blocks/CU.
// ---------------------------------------------------------------------------
__global__ __launch_bounds__(512, 2) void bucket_agg_kernel(
    const unsigned short* __restrict__ hiddenBf,
    const int2* __restrict__ edges, const int* __restrict__ gCursor,
    const float* __restrict__ prelu_a, float* __restrict__ out)
{
    __shared__ float acc[8][NODES_PER_BKT * D_OUT];   // 8 x 8 KB = 64 KB

    const int t      = threadIdx.x;
    const int lane   = t & 63;
    const int wid    = t >> 6;
    const int bucket = blockIdx.x * 8 + wid;
    if (bucket >= N_BKT) return;      // safe: no barriers in this kernel

    float* A = acc[wid];

    // zero this wave's slice: 2048 floats = 512 float4, 8 per lane
    float4* A4 = (float4*)A;
#pragma unroll
    for (int i = 0; i < 8; ++i)
        A4[lane + i * 64] = make_float4(0.f, 0.f, 0.f, 0.f);

    const int base = bucket * BKT_CAP;
    int size = gCursor[bucket];
    if (size > BKT_CAP) size = BKT_CAP;

    for (int i0 = 0; i0 < size; i0 += 64) {
        int take = size - i0;
        if (take > 64) take = 64;
        int2 rec = make_int2(0, 0);
        if (lane < take) rec = edges[base + i0 + lane];

        int j = 0;
        for (; j + 8 <= take; j += 8) {
            int nl[8]; int c[8]; float v[8]; float h[8];
#pragma unroll
            for (int u = 0; u < 8; ++u) {
                int rx = __builtin_amdgcn_readlane(rec.x, j + u);
                nl[u] = (unsigned)rx >> 17;              // node_local in [0,32)
                c[u]  = rx & 0x1FFFF;
                v[u]  = __int_as_float(__builtin_amdgcn_readlane(rec.y, j + u));
            }
#pragma unroll
            for (int u = 0; u < 8; ++u)
                h[u] = __uint_as_float(
                    (unsigned)hiddenBf[(size_t)c[u] * D_OUT + lane] << 16);
            // exclusive slice -> plain RMW; order preserved (alias-unknown)
#pragma unroll
            for (int u = 0; u < 8; ++u)
                A[nl[u] * D_OUT + lane] += v[u] * h[u];
        }
        for (; j < take; ++j) {
            int rx  = __builtin_amdgcn_readlane(rec.x, j);
            float v = __int_as_float(__builtin_amdgcn_readlane(rec.y, j));
            float h = __uint_as_float(
                (unsigned)hiddenBf[(size_t)(rx & 0x1FFFF) * D_OUT + lane] << 16);
            A[((unsigned)rx >> 17) * D_OUT + lane] += v * h;
        }
    }

    // epilogue: PReLU + coalesced store (wave writes its 32 nodes x 64 dims)
    const float a = prelu_a[0];
    const int node0 = bucket * NODES_PER_BKT;
#pragma unroll
    for (int i = 0; i < NODES_PER_BKT; ++i) {
        float s = A[i * D_OUT + lane];
        out[(size_t)(node0 + i) * D_OUT + lane] = s > 0.f ? s : a * s;
    }
}

// ---------------------------------------------------------------------------
extern "C" void kernel_launch(void* const* d_in, const int* in_sizes, int n_in,
                              void* d_out, int out_size, void* d_ws, size_t ws_size,
                              hipStream_t stream)
{
    const float* x       = (const float*)d_in[0];
    const float* w       = (const float*)d_in[1];
    const float* adj     = (const float*)d_in[2];
    const float* prelu_a = (const float*)d_in[3];
    const int*   row     = (const int*)d_in[4];
    const int*   col     = (const int*)d_in[5];
    float* out = (float*)d_out;

    // workspace layout (bytes)
    char* ws = (char*)d_ws;
    unsigned short* hiddenBf = (unsigned short*)(ws);        // 12,800,000
    int2*  edges    = (int2*)        (ws + 12800000);        // 12,800,000 (3125*512*8)
    int*   gCursor  = (int*)         (ws + 25600000);        //     12,500

    hipMemsetAsync(gCursor, 0, N_BKT * sizeof(int), stream);

    gemm_bin_kernel<<<BIN_BLOCKS + GEMM_BLOCKS, 256, 0, stream>>>(
        x, w, hiddenBf, row, col, adj, gCursor, edges);

    bucket_agg_kernel<<<AGG_BLOCKS, 512, 0, stream>>>(
        hiddenBf, edges, gCursor, prelu_a, out);
}